// Round 6
// baseline (174.353 us; speedup 1.0000x reference)
//
#include <hip/hip_runtime.h>
#include <stdint.h>

typedef float f32x4 __attribute__((ext_vector_type(4)));
typedef short bf16x8 __attribute__((ext_vector_type(8)));
typedef float fragc __attribute__((ext_vector_type(4)));
typedef uint32_t u32x4 __attribute__((ext_vector_type(4)));

__device__ __forceinline__ uint32_t pk2(float lo, float hi) {
  // (bf16(lo) | bf16(hi)<<16) via one v_perm_b32 (truncating)
  return __builtin_amdgcn_perm(__float_as_uint(hi), __float_as_uint(lo), 0x07060302u);
}

__device__ __forceinline__ void gload16(const void* g, void* l) {
  __builtin_amdgcn_global_load_lds((const __attribute__((address_space(1))) uint32_t*)g,
                                   (__attribute__((address_space(3))) uint32_t*)l, 16, 0, 0);
}

#define WS_B_OFF 67108864ull  // B'' at ws + 64 MiB

// ---------- Pass 1: [1024 s][512 r][64 h] f32 -> bf16 ws[kq 128][h 64][r 512][16B octet]
// block = (side 2, kq 128, rw 8) = 2048 x 512 thr.
// reads: 2 x 1KB contiguous per wave-instr (100% line util)
// stores: 1KB contiguous per wave-instr; block fills a dense 512KB window (DRAM row friendly)
// LDS bounce [64 h][64 slot][16B], slot = (r + h/4) & 63 -> b128 floor both sides.
__global__ __launch_bounds__(512) void pack_kernel(const float* __restrict__ Ag,
                                                   const float* __restrict__ Bg,
                                                   uint8_t* __restrict__ ws) {
  __shared__ alignas(16) uint8_t lds[65536];

  const int bid  = blockIdx.x;
  const int rw   = bid & 7;
  const int kq   = (bid >> 3) & 127;
  const int side = bid >> 10;
  const int t    = threadIdx.x;

  const f32x4* S4 = (const f32x4*)(side ? Bg : Ag);
  uint8_t* dst = ws + (side ? WS_B_OFF : 0ull);

  // window = rows rw*64..+63 (1024 float4); thread owns rows {t>>4, t>>4+32}, h-quad t&15
  const int base = rw * 1024 + t;
  f32x4 r1[8], r2[8];
#pragma unroll
  for (int e = 0; e < 8; ++e) {
    r1[e] = S4[(size_t)(kq * 8 + e) * 8192 + base];
    r2[e] = S4[(size_t)(kq * 8 + e) * 8192 + base + 512];
  }

  const int hq = t & 15;
  const int ra = t >> 4;  // 0..31
#pragma unroll
  for (int e = 0; e < 4; ++e) {
    const int h = hq * 4 + e;
    u32x4 o1, o2;
    o1[0] = pk2(r1[0][e], r1[1][e]); o1[1] = pk2(r1[2][e], r1[3][e]);
    o1[2] = pk2(r1[4][e], r1[5][e]); o1[3] = pk2(r1[6][e], r1[7][e]);
    o2[0] = pk2(r2[0][e], r2[1][e]); o2[1] = pk2(r2[2][e], r2[3][e]);
    o2[2] = pk2(r2[4][e], r2[5][e]); o2[3] = pk2(r2[6][e], r2[7][e]);
    const int s1 = (ra + hq) & 63;
    const int s2 = (ra + 32 + hq) & 63;
    *(u32x4*)(lds + h * 1024 + s1 * 16) = o1;
    *(u32x4*)(lds + h * 1024 + s2 * 16) = o2;
  }
  __syncthreads();

  const int l = t & 63, w = t >> 6;
#pragma unroll
  for (int e2 = 0; e2 < 8; ++e2) {
    const int h  = e2 * 8 + w;
    const int sl = (l + (h >> 2)) & 63;
    const u32x4 v = *(const u32x4*)(lds + h * 1024 + sl * 16);
    *(u32x4*)(dst + ((size_t)(kq * 64 + h) * 512 + rw * 64 + l) * 16) = v;
  }
}

// ---------- Pass 2: C[i,j,h] = (1/1024) sum_s A''[.,h,i]*B''[.,h,j]
// tile 128i x 64j x 4h, 512 thr (8 waves: hl = w&3, half = w>>2), BK=32,
// SINGLE-buffered LDS 48KB -> 2 blocks/CU (cross-block load/compute overlap).
// grid 512: XCD x owns 4 tiles x all 16 hg (hg fastest) -> C-line writers co-located.
__global__ __launch_bounds__(512, 4) void gemm_kernel(const uint8_t* __restrict__ ws,
                                                      float* __restrict__ Og) {
  __shared__ alignas(16) uint8_t lds[49152];  // A 32KB [hl4][ko4][row128][16B] + B 16KB [hl4][ko4][row64][16B]

  const int bid = blockIdx.x;
  const int x   = bid & 7;
  const int u   = bid >> 3;      // 0..63
  const int hg  = u & 15;
  const int tq  = u >> 4;        // 0..3
  const int i0  = ((x >> 2) * 2 + (tq & 1)) * 128;
  const int j0  = ((x & 3) * 2 + (tq >> 1)) * 64;
  const int hg4 = hg * 4;

  const int t = threadIdx.x, lane = t & 63, w = t >> 6;
  const int hl = w & 3, half = w >> 2;
  const int frl = lane & 15, frg = lane >> 4;

  const uint8_t* Apk = ws;
  const uint8_t* Bpk = ws + WS_B_OFF;

  fragc acc[4][4];
#pragma unroll
  for (int m = 0; m < 4; ++m)
#pragma unroll
    for (int n = 0; n < 4; ++n)
      acc[m][n] = (fragc)0.0f;

  // staging (whole block cooperatively): 4 A-gloads + 2 B-gloads per thread, 1KB/wave-instr
#define ISSUE(kt)                                                                      \
  {                                                                                    \
    _Pragma("unroll") for (int g = 0; g < 4; ++g) {                                    \
      gload16(Apk + ((size_t)((kt) * 4 + (t >> 7)) * 64 + hg4 + g) * 8192 +            \
                  (i0 + (t & 127)) * 16,                                               \
              lds + g * 8192 + t * 16);                                                \
    }                                                                                  \
    _Pragma("unroll") for (int g2 = 0; g2 < 2; ++g2) {                                 \
      gload16(Bpk + ((size_t)((kt) * 4 + ((t >> 6) & 3)) * 64 + hg4 + g2 * 2 +         \
                     (t >> 8)) * 8192 + (j0 + (t & 63)) * 16,                          \
              lds + 32768 + g2 * 8192 + t * 16);                                       \
    }                                                                                  \
  }

  for (int kt = 0; kt < 32; ++kt) {
    __syncthreads();  // all waves done reading LDS tile kt-1
    ISSUE(kt)
    __syncthreads();  // vmcnt drained -> tile kt resident
    const uint8_t* La = lds + hl * 8192;
    const uint8_t* Lb = lds + 32768 + hl * 4096;
    bf16x8 fb[4];
#pragma unroll
    for (int n = 0; n < 4; ++n)
      fb[n] = *(const bf16x8*)(Lb + frg * 1024 + (n * 16 + frl) * 16);
#pragma unroll
    for (int m = 0; m < 4; ++m) {
      bf16x8 fa = *(const bf16x8*)(La + frg * 2048 + (half * 64 + m * 16 + frl) * 16);
#pragma unroll
      for (int n = 0; n < 4; ++n)
        acc[m][n] = __builtin_amdgcn_mfma_f32_16x16x32_bf16(fa, fb[n], acc[m][n], 0, 0, 0);
    }
  }
#undef ISSUE

  // epilogue: bounce C via LDS image [32 il][64 jslot][16B=4h], slot=(j+il)&63 rotation
  // (reads at b128 floor), then 16B/lane stores; L2 merges hg-sibling lines (same XCD).
  const float scale = 1.0f / 1024.0f;
  const int ir = t >> 4, jj = t & 15;
#pragma unroll
  for (int cb = 0; cb < 4; ++cb) {
    __syncthreads();  // previous chunk readers / K-loop readers done
    if (half == (cb >> 1)) {
#pragma unroll
      for (int m2 = 0; m2 < 2; ++m2) {
        const int m = (cb & 1) * 2 + m2;
#pragma unroll
        for (int n = 0; n < 4; ++n) {
#pragma unroll
          for (int q = 0; q < 4; ++q) {
            const int il = m2 * 16 + frg * 4 + q;
            const int j  = n * 16 + frl;
            *(float*)(lds + (il * 64 + ((j + il) & 63)) * 16 + hl * 4) =
                acc[m][n][q] * scale;
          }
        }
      }
    }
    __syncthreads();  // chunk image ready
#pragma unroll
    for (int c = 0; c < 4; ++c) {
      const int jsl = jj * 4 + c;
      const f32x4 v = *(const f32x4*)(lds + (ir * 64 + ((jsl + ir) & 63)) * 16);
      *(f32x4*)(Og + ((size_t)(i0 + cb * 32 + ir) * 512 + j0 + jsl) * 64 + hg4) = v;
    }
  }
}

extern "C" void kernel_launch(void* const* d_in, const int* in_sizes, int n_in,
                              void* d_out, int out_size, void* d_ws, size_t ws_size,
                              hipStream_t stream) {
  const float* a = (const float*)d_in[0];
  const float* b = (const float*)d_in[1];
  float* out = (float*)d_out;
  uint8_t* ws = (uint8_t*)d_ws;
  pack_kernel<<<2048, 512, 0, stream>>>(a, b, ws);
  gemm_kernel<<<512, 512, 0, stream>>>(ws, out);
}